// Round 1
// baseline (314.481 us; speedup 1.0000x reference)
//
#include <hip/hip_runtime.h>
#include <hip/hip_bf16.h>
#include <math.h>

// Problem constants
#define B 64
#define T 1000
#define RNN_DIM 1024
#define EMB_DIM 512
#define ATT_DIM 128
#define LOC_DIM 32
#define KSIZE 31
#define PAD 15          // SAME padding for K=31
#define TILE 50         // t-positions per energy block (20 tiles)
#define CHUNK 50        // t-positions per context block (20 chunks)

// ---------------------------------------------------------------------------
// Kernel 1: pq[b][a] = dot(hidden[b, :1024], Wq[a, :1024])
// One wave per output. 8192 outputs -> 2048 blocks x 256 threads.
// ---------------------------------------------------------------------------
__global__ __launch_bounds__(256) void pq_kernel(
    const float* __restrict__ hidden,   // (B, 1024)
    const float* __restrict__ Wq,       // (128, 1024)
    float* __restrict__ pq)             // (B, 128)
{
    int gwave = (blockIdx.x * blockDim.x + threadIdx.x) >> 6;
    int lane  = threadIdx.x & 63;
    int b = gwave >> 7;     // / 128
    int a = gwave & 127;

    const float4* h4 = (const float4*)(hidden + (size_t)b * RNN_DIM);
    const float4* w4 = (const float4*)(Wq + (size_t)a * RNN_DIM);

    float acc = 0.f;
#pragma unroll
    for (int j = 0; j < 4; ++j) {
        float4 h = h4[j * 64 + lane];
        float4 w = w4[j * 64 + lane];
        acc += h.x * w.x + h.y * w.y + h.z * w.z + h.w * w.w;
    }
#pragma unroll
    for (int off = 32; off > 0; off >>= 1)
        acc += __shfl_down(acc, off, 64);
    if (lane == 0) pq[gwave] = acc;
}

// ---------------------------------------------------------------------------
// Kernel 2: fused location conv + W_loc projection + tanh + v-dot -> energy
// Block = (b, t-tile of TILE). 256 threads.
// ---------------------------------------------------------------------------
__global__ __launch_bounds__(256) void energy_kernel(
    const float* __restrict__ aw,       // (B, 2, T)
    const float* __restrict__ cw,       // (32, 2, 31)
    const float* __restrict__ wl,       // (128, 32)
    const float* __restrict__ pq,       // (B, 128)
    const float* __restrict__ pm,       // (B, T, 128)
    const float* __restrict__ v,        // (128)
    float* __restrict__ energy)         // (B, T)
{
    __shared__ float aw_lds[2][TILE + 2 * PAD];      // 160
    __shared__ float cw_lds[LOC_DIM][2][KSIZE];      // 1984
    __shared__ float wl_lds[ATT_DIM][LOC_DIM + 1];   // +1 pad: 2-way LDS (free)
    __shared__ float pq_lds[ATT_DIM];
    __shared__ float v_lds[ATT_DIM];
    __shared__ float loc_lds[TILE][LOC_DIM];         // broadcast reads in phase 2
    __shared__ float part[4];

    int b   = blockIdx.x;
    int t0  = blockIdx.y * TILE;
    int tid = threadIdx.x;

    for (int i = tid; i < LOC_DIM * 2 * KSIZE; i += 256)
        ((float*)cw_lds)[i] = cw[i];
    for (int i = tid; i < ATT_DIM * LOC_DIM; i += 256)
        wl_lds[i >> 5][i & 31] = wl[i];
    if (tid < ATT_DIM) {
        pq_lds[tid] = pq[b * ATT_DIM + tid];
        v_lds[tid]  = v[tid];
    }
    for (int i = tid; i < 2 * (TILE + 2 * PAD); i += 256) {
        int ch = i / (TILE + 2 * PAD);
        int p  = i % (TILE + 2 * PAD);
        int t  = t0 + p - PAD;
        aw_lds[ch][p] = (t >= 0 && t < T) ? aw[(size_t)b * 2 * T + ch * T + t] : 0.f;
    }
    __syncthreads();

    // Phase 1: loc[t][c] = sum_{ch,k} aw[ch][t+k-PAD] * cw[c][ch][k]
    for (int i = tid; i < TILE * LOC_DIM; i += 256) {
        int t = i >> 5;     // / 32
        int c = i & 31;
        float s = 0.f;
#pragma unroll
        for (int ch = 0; ch < 2; ++ch)
#pragma unroll
            for (int k = 0; k < KSIZE; ++k)
                s += aw_lds[ch][t + k] * cw_lds[c][ch][k];
        loc_lds[t][c] = s;
    }
    __syncthreads();

    // Phase 2: energy[t] = sum_a v[a] * tanh(pq[a] + pm[b,t,a] + W_loc[a,:].loc[:,t])
    int a    = tid & 127;
    int half = tid >> 7;    // which of the 2 t's this iteration
    int wid  = tid >> 6;    // wave id 0..3
    float va  = v_lds[a];
    float pqa = pq_lds[a];

    for (int tp = 0; tp < TILE / 2; ++tp) {
        int tl = tp * 2 + half;
        float e = pqa + pm[(size_t)b * T * ATT_DIM + (size_t)(t0 + tl) * ATT_DIM + a];
#pragma unroll
        for (int c = 0; c < LOC_DIM; ++c)
            e += wl_lds[a][c] * loc_lds[tl][c];
        float contrib = va * tanhf(e);
#pragma unroll
        for (int off = 32; off > 0; off >>= 1)
            contrib += __shfl_down(contrib, off, 64);
        if ((tid & 63) == 0) part[wid] = contrib;
        __syncthreads();
        if (tid == 0)        energy[b * T + t0 + tl] = part[0] + part[1];
        else if (tid == 128) energy[b * T + t0 + tl] = part[2] + part[3];
        __syncthreads();    // protect part[] before next iteration overwrites
    }
}

// ---------------------------------------------------------------------------
// Kernel 3: softmax over T per batch row; writes weights to d_out tail and
// zeroes the context region of d_out (harness poisons d_out with 0xAA).
// ---------------------------------------------------------------------------
__global__ __launch_bounds__(256) void softmax_kernel(
    const float* __restrict__ energy,        // (B, T) in ws
    const unsigned char* __restrict__ mask,  // (B, T) bool
    float* __restrict__ out)                 // [B*512 ctx][B*1000 weights]
{
    int b   = blockIdx.x;
    int tid = threadIdx.x;

    // zero context region for kernel 4's atomics
    for (int i = tid; i < EMB_DIM; i += 256) out[b * EMB_DIM + i] = 0.f;

    __shared__ float red[4];
    float e[4];
    float mx = -INFINITY;
#pragma unroll
    for (int j = 0; j < 4; ++j) {
        int t = tid + j * 256;
        if (t < T) {
            float val = energy[b * T + t];
            if (mask[b * T + t]) val = -INFINITY;
            e[j] = val;
            mx = fmaxf(mx, val);
        } else e[j] = -INFINITY;
    }
#pragma unroll
    for (int off = 32; off > 0; off >>= 1)
        mx = fmaxf(mx, __shfl_down(mx, off, 64));
    if ((tid & 63) == 0) red[tid >> 6] = mx;
    __syncthreads();
    mx = fmaxf(fmaxf(red[0], red[1]), fmaxf(red[2], red[3]));
    __syncthreads();

    float sum = 0.f;
    float ex[4];
#pragma unroll
    for (int j = 0; j < 4; ++j) {
        ex[j] = (e[j] == -INFINITY) ? 0.f : expf(e[j] - mx);
        sum += ex[j];
    }
#pragma unroll
    for (int off = 32; off > 0; off >>= 1)
        sum += __shfl_down(sum, off, 64);
    if ((tid & 63) == 0) red[tid >> 6] = sum;
    __syncthreads();
    sum = red[0] + red[1] + red[2] + red[3];
    float inv = 1.f / sum;
#pragma unroll
    for (int j = 0; j < 4; ++j) {
        int t = tid + j * 256;
        if (t < T) out[B * EMB_DIM + b * T + t] = ex[j] * inv;
    }
}

// ---------------------------------------------------------------------------
// Kernel 4: context[b][e] = sum_t w[b][t] * memory[b][t][e]
// Grid (B, 20 t-chunks); float4-coalesced memory reads; atomicAdd partials.
// ---------------------------------------------------------------------------
__global__ __launch_bounds__(256) void context_kernel(
    const float* __restrict__ memory,   // (B, T, 512)
    const float* __restrict__ w,        // weights at d_out + B*512
    float* __restrict__ ctx)            // d_out context region
{
    int b  = blockIdx.x;
    int t0 = blockIdx.y * CHUNK;
    int e4 = threadIdx.x & 127;   // float4 index within 512
    int ts = threadIdx.x >> 7;    // 0/1: t interleave

    const float4* mem4 = (const float4*)(memory + (size_t)b * T * EMB_DIM);
    float4 acc = {0.f, 0.f, 0.f, 0.f};
    for (int t = t0 + ts; t < t0 + CHUNK; t += 2) {
        float wt = w[b * T + t];           // wave-uniform -> broadcast
        float4 m = mem4[(size_t)t * 128 + e4];
        acc.x += wt * m.x; acc.y += wt * m.y;
        acc.z += wt * m.z; acc.w += wt * m.w;
    }
    float* dst = ctx + b * EMB_DIM + e4 * 4;
    atomicAdd(dst + 0, acc.x);
    atomicAdd(dst + 1, acc.y);
    atomicAdd(dst + 2, acc.z);
    atomicAdd(dst + 3, acc.w);
}

// ---------------------------------------------------------------------------
extern "C" void kernel_launch(void* const* d_in, const int* in_sizes, int n_in,
                              void* d_out, int out_size, void* d_ws, size_t ws_size,
                              hipStream_t stream) {
    const float* hidden = (const float*)d_in[0];            // (64, 1024)
    const float* memory = (const float*)d_in[1];            // (64, 1000, 512)
    const float* pm     = (const float*)d_in[2];            // (64, 1000, 128)
    const float* aw     = (const float*)d_in[3];            // (64, 2, 1000)
    const unsigned char* mask = (const unsigned char*)d_in[4]; // (64, 1000) bool
    const float* Wq     = (const float*)d_in[5];            // (128, 1024)
    const float* cw     = (const float*)d_in[6];            // (32, 2, 31)
    const float* wl     = (const float*)d_in[7];            // (128, 32)
    const float* v      = (const float*)d_in[8];            // (1, 128)

    float* out = (float*)d_out;            // [B*512 context][B*1000 weights]

    // workspace layout
    float* pq_ws     = (float*)d_ws;                   // B*128
    float* energy_ws = pq_ws + B * ATT_DIM;            // B*T

    // 1) query projection: 8192 waves
    pq_kernel<<<dim3((B * ATT_DIM) / 4), dim3(256), 0, stream>>>(hidden, Wq, pq_ws);

    // 2) fused conv/proj/tanh/v-dot -> energy
    energy_kernel<<<dim3(B, T / TILE), dim3(256), 0, stream>>>(
        aw, cw, wl, pq_ws, pm, v, energy_ws);

    // 3) softmax (writes weights to out tail, zeroes context region)
    softmax_kernel<<<dim3(B), dim3(256), 0, stream>>>(energy_ws, mask, out);

    // 4) context accumulation
    context_kernel<<<dim3(B, T / CHUNK), dim3(256), 0, stream>>>(
        memory, out + B * EMB_DIM, out);
}

// Round 3
// 281.437 us; speedup vs baseline: 1.1174x; 1.1174x over previous
//
#include <hip/hip_runtime.h>
#include <hip/hip_bf16.h>
#include <math.h>

// Problem constants
#define B 64
#define T 1000
#define RNN_DIM 1024
#define EMB_DIM 512
#define ATT_DIM 128
#define LOC_DIM 32
#define KSIZE 31
#define PAD 15          // SAME padding for K=31
#define ET 64           // t-positions per energy block (16 tiles, last partial)
#define CHUNK 50        // t-positions per context block (20 chunks)

// ---------------------------------------------------------------------------
// Kernel 1: pq[b][a] = dot(hidden[b, :1024], Wq[a, :1024])
// One wave per output. 8192 outputs -> 2048 blocks x 256 threads.
// ---------------------------------------------------------------------------
__global__ __launch_bounds__(256) void pq_kernel(
    const float* __restrict__ hidden,   // (B, 1024)
    const float* __restrict__ Wq,       // (128, 1024)
    float* __restrict__ pq)             // (B, 128)
{
    int gwave = (blockIdx.x * blockDim.x + threadIdx.x) >> 6;
    int lane  = threadIdx.x & 63;
    int b = gwave >> 7;     // / 128
    int a = gwave & 127;

    const float4* h4 = (const float4*)(hidden + (size_t)b * RNN_DIM);
    const float4* w4 = (const float4*)(Wq + (size_t)a * RNN_DIM);

    float acc = 0.f;
#pragma unroll
    for (int j = 0; j < 4; ++j) {
        float4 h = h4[j * 64 + lane];
        float4 w = w4[j * 64 + lane];
        acc += h.x * w.x + h.y * w.y + h.z * w.z + h.w * w.w;
    }
#pragma unroll
    for (int off = 32; off > 0; off >>= 1)
        acc += __shfl_down(acc, off, 64);
    if (lane == 0) pq[gwave] = acc;
}

// ---------------------------------------------------------------------------
// Kernel 2: fused location conv + W_loc projection + tanh + v-dot -> energy.
// Block = (b, 64-t tile), 256 threads, 3 barriers total (was 53).
// Phase 1: conv with aw window + accumulators in registers.
// Phase 2: thread = (t, a-quarter), a interleaved so wl b128 reads are
//          conflict-free; loc row in registers; 2-shfl reduction.
// ---------------------------------------------------------------------------
__global__ __launch_bounds__(256) void energy_kernel(
    const float* __restrict__ aw,       // (B, 2, T)
    const float* __restrict__ cw,       // (32, 2, 31)
    const float* __restrict__ wl,       // (128, 32)
    const float* __restrict__ pq,       // (B, 128)
    const float* __restrict__ pm,       // (B, T, 128)
    const float* __restrict__ v,        // (128)
    float* __restrict__ energy)         // (B, T)
{
    __shared__ float aw_lds[2][ET + 2 * PAD];     // [2][94]
    __shared__ float cw_lds[LOC_DIM][2][KSIZE];   // bank: 30c%32 -> 2-way, free
    __shared__ float wl_lds[ATT_DIM][36];         // stride 36: b128-aligned, 4 distinct banks across aq
    __shared__ float pq_lds[ATT_DIM];
    __shared__ float v_lds[ATT_DIM];
    __shared__ float loc_lds[ET][36];             // stride 36: b128 reads 2-way (free)
    __shared__ float pm_lds[ET][132];             // stride 132: b32 reads 2-way (free)

    const int b   = blockIdx.x;
    const int t0  = blockIdx.y * ET;
    const int tid = threadIdx.x;

    // ---- stage pm tile: (64 t x 128 a) float4-coalesced (512B per row) ----
    const float4* pm4 = (const float4*)(pm + (size_t)b * T * ATT_DIM);
    for (int i = tid; i < ET * 32; i += 256) {
        int t = i >> 5, c4 = i & 31;
        int tt = t0 + t;
        float4 val = make_float4(0.f, 0.f, 0.f, 0.f);
        if (tt < T) val = pm4[(size_t)tt * 32 + c4];
        *((float4*)&pm_lds[t][c4 * 4]) = val;
    }
    // ---- stage small weights ----
    for (int i = tid; i < LOC_DIM * 2 * KSIZE; i += 256)
        ((float*)cw_lds)[i] = cw[i];
    for (int i = tid; i < ATT_DIM * LOC_DIM; i += 256)
        wl_lds[i >> 5][i & 31] = wl[i];
    if (tid < ATT_DIM) {
        pq_lds[tid] = pq[b * ATT_DIM + tid];
        v_lds[tid]  = v[tid];
    }
    for (int i = tid; i < 2 * (ET + 2 * PAD); i += 256) {
        int ch = i / (ET + 2 * PAD);
        int p  = i % (ET + 2 * PAD);
        int t  = t0 + p - PAD;
        aw_lds[ch][p] = (t >= 0 && t < T) ? aw[(size_t)b * 2 * T + ch * T + t] : 0.f;
    }
    __syncthreads();

    // ---- Phase 1: conv. thread = (c = tid&31, tg = tid>>5), 8 t's each ----
    {
        const int c  = tid & 31;
        const int tg = tid >> 5;
        float acc[8];
#pragma unroll
        for (int j = 0; j < 8; ++j) acc[j] = 0.f;
#pragma unroll
        for (int ch = 0; ch < 2; ++ch) {
            float awr[KSIZE + 7];   // 38-float sliding window in registers
#pragma unroll
            for (int j = 0; j < KSIZE + 7; ++j) awr[j] = aw_lds[ch][tg * 8 + j];
#pragma unroll
            for (int k = 0; k < KSIZE; ++k) {
                float cv = cw_lds[c][ch][k];   // 2-way broadcast, free
#pragma unroll
                for (int j = 0; j < 8; ++j) acc[j] += cv * awr[k + j];
            }
        }
#pragma unroll
        for (int j = 0; j < 8; ++j) loc_lds[tg * 8 + j][c] = acc[j];
    }
    __syncthreads();

    // ---- Phase 2: thread = (tl = tid>>2, aq = tid&3), a = aq + 4*aa ----
    {
        const int tl = tid >> 2;
        const int aq = tid & 3;

        float lr[32];   // loc row in registers
#pragma unroll
        for (int j = 0; j < 8; ++j)
            *((float4*)&lr[4 * j]) = *((const float4*)&loc_lds[tl][4 * j]);

        float acc = 0.f;
#pragma unroll 4
        for (int aa = 0; aa < 32; ++aa) {
            const int a = aq + 4 * aa;   // interleaved: 4 lanes -> 4 distinct banks
            float e = pq_lds[a] + pm_lds[tl][a];
#pragma unroll
            for (int j = 0; j < 8; ++j) {
                float4 w4 = *((const float4*)&wl_lds[a][4 * j]);
                e += w4.x * lr[4*j] + w4.y * lr[4*j+1] + w4.z * lr[4*j+2] + w4.w * lr[4*j+3];
            }
            // fast tanh: 1 - 2/(1+exp(2e)); ~5 VALU ops, abs err ~1e-6
            float ex = __expf(2.f * e);
            float th = 1.f - 2.f * __builtin_amdgcn_rcpf(1.f + ex);
            acc += v_lds[a] * th;
        }
        // reduce the 4 adjacent lanes sharing t
        acc += __shfl_xor(acc, 1, 64);
        acc += __shfl_xor(acc, 2, 64);
        if (aq == 0 && (t0 + tl) < T)
            energy[b * T + t0 + tl] = acc;
    }
}

// ---------------------------------------------------------------------------
// Kernel 3: softmax over T per batch row; writes weights to d_out tail and
// zeroes the context region of d_out (harness poisons d_out with 0xAA).
// ---------------------------------------------------------------------------
__global__ __launch_bounds__(256) void softmax_kernel(
    const float* __restrict__ energy,        // (B, T) in ws
    const unsigned char* __restrict__ mask,  // (B, T) bool
    float* __restrict__ out)                 // [B*512 ctx][B*1000 weights]
{
    int b   = blockIdx.x;
    int tid = threadIdx.x;

    // zero context region for kernel 4's atomics
    for (int i = tid; i < EMB_DIM; i += 256) out[b * EMB_DIM + i] = 0.f;

    __shared__ float red[4];
    float e[4];
    float mx = -INFINITY;
#pragma unroll
    for (int j = 0; j < 4; ++j) {
        int t = tid + j * 256;
        if (t < T) {
            float val = energy[b * T + t];
            if (mask[b * T + t]) val = -INFINITY;
            e[j] = val;
            mx = fmaxf(mx, val);
        } else e[j] = -INFINITY;
    }
#pragma unroll
    for (int off = 32; off > 0; off >>= 1)
        mx = fmaxf(mx, __shfl_down(mx, off, 64));
    if ((tid & 63) == 0) red[tid >> 6] = mx;
    __syncthreads();
    mx = fmaxf(fmaxf(red[0], red[1]), fmaxf(red[2], red[3]));
    __syncthreads();

    float sum = 0.f;
    float ex[4];
#pragma unroll
    for (int j = 0; j < 4; ++j) {
        ex[j] = (e[j] == -INFINITY) ? 0.f : expf(e[j] - mx);
        sum += ex[j];
    }
#pragma unroll
    for (int off = 32; off > 0; off >>= 1)
        sum += __shfl_down(sum, off, 64);
    if ((tid & 63) == 0) red[tid >> 6] = sum;
    __syncthreads();
    sum = red[0] + red[1] + red[2] + red[3];
    float inv = 1.f / sum;
#pragma unroll
    for (int j = 0; j < 4; ++j) {
        int t = tid + j * 256;
        if (t < T) out[B * EMB_DIM + b * T + t] = ex[j] * inv;
    }
}

// ---------------------------------------------------------------------------
// Kernel 4: context[b][e] = sum_t w[b][t] * memory[b][t][e]
// Grid (B, 20 t-chunks); float4-coalesced memory reads; atomicAdd partials
// (~40 atomics/address -> negligible contention).
// ---------------------------------------------------------------------------
__global__ __launch_bounds__(256) void context_kernel(
    const float* __restrict__ memory,   // (B, T, 512)
    const float* __restrict__ w,        // weights at d_out + B*512
    float* __restrict__ ctx)            // d_out context region
{
    int b  = blockIdx.x;
    int t0 = blockIdx.y * CHUNK;
    int e4 = threadIdx.x & 127;   // float4 index within 512
    int ts = threadIdx.x >> 7;    // 0/1: t interleave

    const float4* mem4 = (const float4*)(memory + (size_t)b * T * EMB_DIM);
    float4 acc = {0.f, 0.f, 0.f, 0.f};
    for (int t = t0 + ts; t < t0 + CHUNK; t += 2) {
        float wt = w[b * T + t];           // wave-uniform -> broadcast
        float4 m = mem4[(size_t)t * 128 + e4];
        acc.x += wt * m.x; acc.y += wt * m.y;
        acc.z += wt * m.z; acc.w += wt * m.w;
    }
    float* dst = ctx + b * EMB_DIM + e4 * 4;
    atomicAdd(dst + 0, acc.x);
    atomicAdd(dst + 1, acc.y);
    atomicAdd(dst + 2, acc.z);
    atomicAdd(dst + 3, acc.w);
}

// ---------------------------------------------------------------------------
extern "C" void kernel_launch(void* const* d_in, const int* in_sizes, int n_in,
                              void* d_out, int out_size, void* d_ws, size_t ws_size,
                              hipStream_t stream) {
    const float* hidden = (const float*)d_in[0];            // (64, 1024)
    const float* memory = (const float*)d_in[1];            // (64, 1000, 512)
    const float* pm     = (const float*)d_in[2];            // (64, 1000, 128)
    const float* aw     = (const float*)d_in[3];            // (64, 2, 1000)
    const unsigned char* mask = (const unsigned char*)d_in[4]; // (64, 1000) bool
    const float* Wq     = (const float*)d_in[5];            // (128, 1024)
    const float* cw     = (const float*)d_in[6];            // (32, 2, 31)
    const float* wl     = (const float*)d_in[7];            // (128, 32)
    const float* v      = (const float*)d_in[8];            // (1, 128)

    float* out = (float*)d_out;            // [B*512 context][B*1000 weights]

    // workspace layout
    float* pq_ws     = (float*)d_ws;                   // B*128
    float* energy_ws = pq_ws + B * ATT_DIM;            // B*T

    // 1) query projection: 8192 waves
    pq_kernel<<<dim3((B * ATT_DIM) / 4), dim3(256), 0, stream>>>(hidden, Wq, pq_ws);

    // 2) fused conv/proj/tanh/v-dot -> energy  (16 tiles of 64 t)
    energy_kernel<<<dim3(B, (T + ET - 1) / ET), dim3(256), 0, stream>>>(
        aw, cw, wl, pq_ws, pm, v, energy_ws);

    // 3) softmax (writes weights to out tail, zeroes context region)
    softmax_kernel<<<dim3(B), dim3(256), 0, stream>>>(energy_ws, mask, out);

    // 4) context accumulation
    context_kernel<<<dim3(B, T / CHUNK), dim3(256), 0, stream>>>(
        memory, out + B * EMB_DIM, out);
}

// Round 4
// 266.989 us; speedup vs baseline: 1.1779x; 1.0541x over previous
//
#include <hip/hip_runtime.h>
#include <hip/hip_bf16.h>
#include <math.h>

// Problem constants
#define B 64
#define T 1000
#define RNN_DIM 1024
#define EMB_DIM 512
#define ATT_DIM 128
#define LOC_DIM 32
#define KSIZE 31
#define PAD 15          // SAME padding for K=31
#define ET 64           // t-positions per energy block (16 tiles, last partial)
#define CHUNK 100       // t-positions per context block (10 chunks)

// ---------------------------------------------------------------------------
// Kernel 1: pq[b][a] = dot(hidden[b, :1024], Wq[a, :1024])
// One wave per output. 8192 outputs -> 2048 blocks x 256 threads.
// ---------------------------------------------------------------------------
__global__ __launch_bounds__(256) void pq_kernel(
    const float* __restrict__ hidden,   // (B, 1024)
    const float* __restrict__ Wq,       // (128, 1024)
    float* __restrict__ pq)             // (B, 128)
{
    int gwave = (blockIdx.x * blockDim.x + threadIdx.x) >> 6;
    int lane  = threadIdx.x & 63;
    int b = gwave >> 7;     // / 128
    int a = gwave & 127;

    const float4* h4 = (const float4*)(hidden + (size_t)b * RNN_DIM);
    const float4* w4 = (const float4*)(Wq + (size_t)a * RNN_DIM);

    float acc = 0.f;
#pragma unroll
    for (int j = 0; j < 4; ++j) {
        float4 h = h4[j * 64 + lane];
        float4 w = w4[j * 64 + lane];
        acc += h.x * w.x + h.y * w.y + h.z * w.z + h.w * w.w;
    }
#pragma unroll
    for (int off = 32; off > 0; off >>= 1)
        acc += __shfl_down(acc, off, 64);
    if (lane == 0) pq[gwave] = acc;
}

// ---------------------------------------------------------------------------
// Kernel 2: fused location conv + W_loc projection + tanh + v-dot -> energy.
// Block = (b, 64-t tile), 256 threads, 3 barriers total.
// (R2 win: 78 us -> off the top-5; structure unchanged.)
// ---------------------------------------------------------------------------
__global__ __launch_bounds__(256) void energy_kernel(
    const float* __restrict__ aw,       // (B, 2, T)
    const float* __restrict__ cw,       // (32, 2, 31)
    const float* __restrict__ wl,       // (128, 32)
    const float* __restrict__ pq,       // (B, 128)
    const float* __restrict__ pm,       // (B, T, 128)
    const float* __restrict__ v,        // (128)
    float* __restrict__ energy)         // (B, T)
{
    __shared__ float aw_lds[2][ET + 2 * PAD];     // [2][94]
    __shared__ float cw_lds[LOC_DIM][2][KSIZE];   // bank: 2-way, free
    __shared__ float wl_lds[ATT_DIM][36];         // stride 36: 4 distinct banks across aq
    __shared__ float pq_lds[ATT_DIM];
    __shared__ float v_lds[ATT_DIM];
    __shared__ float loc_lds[ET][36];             // stride 36: b128 reads 2-way (free)
    __shared__ float pm_lds[ET][132];             // stride 132: b32 reads 2-way (free)

    const int b   = blockIdx.x;
    const int t0  = blockIdx.y * ET;
    const int tid = threadIdx.x;

    // ---- stage pm tile: (64 t x 128 a) float4-coalesced (512B per row) ----
    const float4* pm4 = (const float4*)(pm + (size_t)b * T * ATT_DIM);
    for (int i = tid; i < ET * 32; i += 256) {
        int t = i >> 5, c4 = i & 31;
        int tt = t0 + t;
        float4 val = make_float4(0.f, 0.f, 0.f, 0.f);
        if (tt < T) val = pm4[(size_t)tt * 32 + c4];
        *((float4*)&pm_lds[t][c4 * 4]) = val;
    }
    // ---- stage small weights ----
    for (int i = tid; i < LOC_DIM * 2 * KSIZE; i += 256)
        ((float*)cw_lds)[i] = cw[i];
    for (int i = tid; i < ATT_DIM * LOC_DIM; i += 256)
        wl_lds[i >> 5][i & 31] = wl[i];
    if (tid < ATT_DIM) {
        pq_lds[tid] = pq[b * ATT_DIM + tid];
        v_lds[tid]  = v[tid];
    }
    for (int i = tid; i < 2 * (ET + 2 * PAD); i += 256) {
        int ch = i / (ET + 2 * PAD);
        int p  = i % (ET + 2 * PAD);
        int t  = t0 + p - PAD;
        aw_lds[ch][p] = (t >= 0 && t < T) ? aw[(size_t)b * 2 * T + ch * T + t] : 0.f;
    }
    __syncthreads();

    // ---- Phase 1: conv. thread = (c = tid&31, tg = tid>>5), 8 t's each ----
    {
        const int c  = tid & 31;
        const int tg = tid >> 5;
        float acc[8];
#pragma unroll
        for (int j = 0; j < 8; ++j) acc[j] = 0.f;
#pragma unroll
        for (int ch = 0; ch < 2; ++ch) {
            float awr[KSIZE + 7];   // 38-float sliding window in registers
#pragma unroll
            for (int j = 0; j < KSIZE + 7; ++j) awr[j] = aw_lds[ch][tg * 8 + j];
#pragma unroll
            for (int k = 0; k < KSIZE; ++k) {
                float cv = cw_lds[c][ch][k];   // 2-way broadcast, free
#pragma unroll
                for (int j = 0; j < 8; ++j) acc[j] += cv * awr[k + j];
            }
        }
#pragma unroll
        for (int j = 0; j < 8; ++j) loc_lds[tg * 8 + j][c] = acc[j];
    }
    __syncthreads();

    // ---- Phase 2: thread = (tl = tid>>2, aq = tid&3), a = aq + 4*aa ----
    {
        const int tl = tid >> 2;
        const int aq = tid & 3;

        float lr[32];   // loc row in registers
#pragma unroll
        for (int j = 0; j < 8; ++j)
            *((float4*)&lr[4 * j]) = *((const float4*)&loc_lds[tl][4 * j]);

        float acc = 0.f;
#pragma unroll 4
        for (int aa = 0; aa < 32; ++aa) {
            const int a = aq + 4 * aa;   // interleaved: 4 lanes -> 4 distinct banks
            float e = pq_lds[a] + pm_lds[tl][a];
#pragma unroll
            for (int j = 0; j < 8; ++j) {
                float4 w4 = *((const float4*)&wl_lds[a][4 * j]);
                e += w4.x * lr[4*j] + w4.y * lr[4*j+1] + w4.z * lr[4*j+2] + w4.w * lr[4*j+3];
            }
            // fast tanh: 1 - 2/(1+exp(2e)); ~5 VALU ops, abs err ~1e-6
            float ex = __expf(2.f * e);
            float th = 1.f - 2.f * __builtin_amdgcn_rcpf(1.f + ex);
            acc += v_lds[a] * th;
        }
        // reduce the 4 adjacent lanes sharing t
        acc += __shfl_xor(acc, 1, 64);
        acc += __shfl_xor(acc, 2, 64);
        if (aq == 0 && (t0 + tl) < T)
            energy[b * T + t0 + tl] = acc;
    }
}

// ---------------------------------------------------------------------------
// Kernel 3: softmax over T per batch row; writes weights to d_out tail and
// zeroes the context region of d_out (harness poisons d_out with 0xAA).
// ---------------------------------------------------------------------------
__global__ __launch_bounds__(256) void softmax_kernel(
    const float* __restrict__ energy,        // (B, T) in ws
    const unsigned char* __restrict__ mask,  // (B, T) bool
    float* __restrict__ out)                 // [B*512 ctx][B*1000 weights]
{
    int b   = blockIdx.x;
    int tid = threadIdx.x;

    // zero context region for kernel 4's atomics
    for (int i = tid; i < EMB_DIM; i += 256) out[b * EMB_DIM + i] = 0.f;

    __shared__ float red[4];
    float e[4];
    float mx = -INFINITY;
#pragma unroll
    for (int j = 0; j < 4; ++j) {
        int t = tid + j * 256;
        if (t < T) {
            float val = energy[b * T + t];
            if (mask[b * T + t]) val = -INFINITY;
            e[j] = val;
            mx = fmaxf(mx, val);
        } else e[j] = -INFINITY;
    }
#pragma unroll
    for (int off = 32; off > 0; off >>= 1)
        mx = fmaxf(mx, __shfl_down(mx, off, 64));
    if ((tid & 63) == 0) red[tid >> 6] = mx;
    __syncthreads();
    mx = fmaxf(fmaxf(red[0], red[1]), fmaxf(red[2], red[3]));
    __syncthreads();

    float sum = 0.f;
    float ex[4];
#pragma unroll
    for (int j = 0; j < 4; ++j) {
        ex[j] = (e[j] == -INFINITY) ? 0.f : expf(e[j] - mx);
        sum += ex[j];
    }
#pragma unroll
    for (int off = 32; off > 0; off >>= 1)
        sum += __shfl_down(sum, off, 64);
    if ((tid & 63) == 0) red[tid >> 6] = sum;
    __syncthreads();
    sum = red[0] + red[1] + red[2] + red[3];
    float inv = 1.f / sum;
#pragma unroll
    for (int j = 0; j < 4; ++j) {
        int t = tid + j * 256;
        if (t < T) out[B * EMB_DIM + b * T + t] = ex[j] * inv;
    }
}

// ---------------------------------------------------------------------------
// Kernel 4: context[b][e] = sum_t w[b][t] * memory[b][t][e]
// R3 was latency-bound (VGPR_Count=8 -> ~1 load in flight, hbm 12%).
// New: thread = (e8 = lane, ts = wave). Each thread reads 2 consecutive
// float4s/t (wave covers the full 2KB row); t-loop unrolled x5 -> 10
// independent dwordx4 loads in flight. Weights staged in LDS (broadcast
// read, off the critical path). Block-level LDS reduction -> 1 atomic per
// output float per block (327k total, was 1.31M).
// ---------------------------------------------------------------------------
__global__ __launch_bounds__(256) void context_kernel(
    const float* __restrict__ memory,   // (B, T, 512)
    const float* __restrict__ w,        // weights at d_out + B*512
    float* __restrict__ ctx)            // d_out context region
{
    __shared__ float w_lds[CHUNK];
    __shared__ float red[4][EMB_DIM];   // 8 KB partials

    const int b   = blockIdx.x;
    const int t0  = blockIdx.y * CHUNK;
    const int tid = threadIdx.x;
    const int e8  = tid & 63;   // pair-of-float4 index within 512-float row
    const int ts  = tid >> 6;   // wave id 0..3: t interleave

    if (tid < CHUNK) w_lds[tid] = w[b * T + t0 + tid];
    __syncthreads();

    const float4* mem4 = (const float4*)(memory + (size_t)b * T * EMB_DIM);
    float4 acc0 = {0.f, 0.f, 0.f, 0.f};
    float4 acc1 = {0.f, 0.f, 0.f, 0.f};

#pragma unroll 5
    for (int i = 0; i < CHUNK / 4; ++i) {
        int t = ts + 4 * i;                    // wave-uniform
        float wt = w_lds[t];                   // LDS broadcast
        const float4* row = mem4 + (size_t)(t0 + t) * 128 + e8 * 2;
        float4 m0 = row[0];
        float4 m1 = row[1];
        acc0.x += wt * m0.x; acc0.y += wt * m0.y;
        acc0.z += wt * m0.z; acc0.w += wt * m0.w;
        acc1.x += wt * m1.x; acc1.y += wt * m1.y;
        acc1.z += wt * m1.z; acc1.w += wt * m1.w;
    }

    // block reduction: 4 t-interleave waves hit the same 8 output floats
    float* r = &red[ts][e8 * 8];
    r[0] = acc0.x; r[1] = acc0.y; r[2] = acc0.z; r[3] = acc0.w;
    r[4] = acc1.x; r[5] = acc1.y; r[6] = acc1.z; r[7] = acc1.w;
    __syncthreads();
    for (int i = tid; i < EMB_DIM; i += 256) {
        float s = red[0][i] + red[1][i] + red[2][i] + red[3][i];
        atomicAdd(ctx + b * EMB_DIM + i, s);
    }
}

// ---------------------------------------------------------------------------
extern "C" void kernel_launch(void* const* d_in, const int* in_sizes, int n_in,
                              void* d_out, int out_size, void* d_ws, size_t ws_size,
                              hipStream_t stream) {
    const float* hidden = (const float*)d_in[0];            // (64, 1024)
    const float* memory = (const float*)d_in[1];            // (64, 1000, 512)
    const float* pm     = (const float*)d_in[2];            // (64, 1000, 128)
    const float* aw     = (const float*)d_in[3];            // (64, 2, 1000)
    const unsigned char* mask = (const unsigned char*)d_in[4]; // (64, 1000) bool
    const float* Wq     = (const float*)d_in[5];            // (128, 1024)
    const float* cw     = (const float*)d_in[6];            // (32, 2, 31)
    const float* wl     = (const float*)d_in[7];            // (128, 32)
    const float* v      = (const float*)d_in[8];            // (1, 128)

    float* out = (float*)d_out;            // [B*512 context][B*1000 weights]

    // workspace layout
    float* pq_ws     = (float*)d_ws;                   // B*128
    float* energy_ws = pq_ws + B * ATT_DIM;            // B*T

    // 1) query projection: 8192 waves
    pq_kernel<<<dim3((B * ATT_DIM) / 4), dim3(256), 0, stream>>>(hidden, Wq, pq_ws);

    // 2) fused conv/proj/tanh/v-dot -> energy  (16 tiles of 64 t)
    energy_kernel<<<dim3(B, (T + ET - 1) / ET), dim3(256), 0, stream>>>(
        aw, cw, wl, pq_ws, pm, v, energy_ws);

    // 3) softmax (writes weights to out tail, zeroes context region)
    softmax_kernel<<<dim3(B), dim3(256), 0, stream>>>(energy_ws, mask, out);

    // 4) context accumulation (10 chunks of 100 t)
    context_kernel<<<dim3(B, T / CHUNK), dim3(256), 0, stream>>>(
        memory, out + B * EMB_DIM, out);
}

// Round 5
// 266.576 us; speedup vs baseline: 1.1797x; 1.0015x over previous
//
#include <hip/hip_runtime.h>
#include <hip/hip_bf16.h>
#include <math.h>

// Problem constants
#define B 64
#define T 1000
#define RNN_DIM 1024
#define EMB_DIM 512
#define ATT_DIM 128
#define LOC_DIM 32
#define KSIZE 31
#define PAD 15          // SAME padding for K=31
#define ET 64           // t-positions per energy block (16 tiles, last partial)
#define CHUNK 40        // t-positions per context block (25 chunks)

// ---------------------------------------------------------------------------
// Kernel 1: pq[b][a] = dot(hidden[b, :1024], Wq[a, :1024])
// One wave per output. 8192 outputs -> 2048 blocks x 256 threads.
// ---------------------------------------------------------------------------
__global__ __launch_bounds__(256) void pq_kernel(
    const float* __restrict__ hidden,   // (B, 1024)
    const float* __restrict__ Wq,       // (128, 1024)
    float* __restrict__ pq)             // (B, 128)
{
    int gwave = (blockIdx.x * blockDim.x + threadIdx.x) >> 6;
    int lane  = threadIdx.x & 63;
    int b = gwave >> 7;     // / 128
    int a = gwave & 127;

    const float4* h4 = (const float4*)(hidden + (size_t)b * RNN_DIM);
    const float4* w4 = (const float4*)(Wq + (size_t)a * RNN_DIM);

    float acc = 0.f;
#pragma unroll
    for (int j = 0; j < 4; ++j) {
        float4 h = h4[j * 64 + lane];
        float4 w = w4[j * 64 + lane];
        acc += h.x * w.x + h.y * w.y + h.z * w.z + h.w * w.w;
    }
#pragma unroll
    for (int off = 32; off > 0; off >>= 1)
        acc += __shfl_down(acc, off, 64);
    if (lane == 0) pq[gwave] = acc;
}

// ---------------------------------------------------------------------------
// Kernel 2: fused location conv + W_loc projection + tanh + v-dot -> energy.
// Block = (b, 64-t tile), 256 threads, 3 barriers total.
// (R2 win: 78 us -> off the top-5; structure unchanged.)
// ---------------------------------------------------------------------------
__global__ __launch_bounds__(256) void energy_kernel(
    const float* __restrict__ aw,       // (B, 2, T)
    const float* __restrict__ cw,       // (32, 2, 31)
    const float* __restrict__ wl,       // (128, 32)
    const float* __restrict__ pq,       // (B, 128)
    const float* __restrict__ pm,       // (B, T, 128)
    const float* __restrict__ v,        // (128)
    float* __restrict__ energy)         // (B, T)
{
    __shared__ float aw_lds[2][ET + 2 * PAD];     // [2][94]
    __shared__ float cw_lds[LOC_DIM][2][KSIZE];   // bank: 2-way, free
    __shared__ float wl_lds[ATT_DIM][36];         // stride 36: 4 distinct banks across aq
    __shared__ float pq_lds[ATT_DIM];
    __shared__ float v_lds[ATT_DIM];
    __shared__ float loc_lds[ET][36];             // stride 36: b128 reads 2-way (free)
    __shared__ float pm_lds[ET][132];             // stride 132: b32 reads 2-way (free)

    const int b   = blockIdx.x;
    const int t0  = blockIdx.y * ET;
    const int tid = threadIdx.x;

    // ---- stage pm tile: (64 t x 128 a) float4-coalesced (512B per row) ----
    const float4* pm4 = (const float4*)(pm + (size_t)b * T * ATT_DIM);
    for (int i = tid; i < ET * 32; i += 256) {
        int t = i >> 5, c4 = i & 31;
        int tt = t0 + t;
        float4 val = make_float4(0.f, 0.f, 0.f, 0.f);
        if (tt < T) val = pm4[(size_t)tt * 32 + c4];
        *((float4*)&pm_lds[t][c4 * 4]) = val;
    }
    // ---- stage small weights ----
    for (int i = tid; i < LOC_DIM * 2 * KSIZE; i += 256)
        ((float*)cw_lds)[i] = cw[i];
    for (int i = tid; i < ATT_DIM * LOC_DIM; i += 256)
        wl_lds[i >> 5][i & 31] = wl[i];
    if (tid < ATT_DIM) {
        pq_lds[tid] = pq[b * ATT_DIM + tid];
        v_lds[tid]  = v[tid];
    }
    for (int i = tid; i < 2 * (ET + 2 * PAD); i += 256) {
        int ch = i / (ET + 2 * PAD);
        int p  = i % (ET + 2 * PAD);
        int t  = t0 + p - PAD;
        aw_lds[ch][p] = (t >= 0 && t < T) ? aw[(size_t)b * 2 * T + ch * T + t] : 0.f;
    }
    __syncthreads();

    // ---- Phase 1: conv. thread = (c = tid&31, tg = tid>>5), 8 t's each ----
    {
        const int c  = tid & 31;
        const int tg = tid >> 5;
        float acc[8];
#pragma unroll
        for (int j = 0; j < 8; ++j) acc[j] = 0.f;
#pragma unroll
        for (int ch = 0; ch < 2; ++ch) {
            float awr[KSIZE + 7];   // 38-float sliding window in registers
#pragma unroll
            for (int j = 0; j < KSIZE + 7; ++j) awr[j] = aw_lds[ch][tg * 8 + j];
#pragma unroll
            for (int k = 0; k < KSIZE; ++k) {
                float cv = cw_lds[c][ch][k];   // 2-way broadcast, free
#pragma unroll
                for (int j = 0; j < 8; ++j) acc[j] += cv * awr[k + j];
            }
        }
#pragma unroll
        for (int j = 0; j < 8; ++j) loc_lds[tg * 8 + j][c] = acc[j];
    }
    __syncthreads();

    // ---- Phase 2: thread = (tl = tid>>2, aq = tid&3), a = aq + 4*aa ----
    {
        const int tl = tid >> 2;
        const int aq = tid & 3;

        float lr[32];   // loc row in registers
#pragma unroll
        for (int j = 0; j < 8; ++j)
            *((float4*)&lr[4 * j]) = *((const float4*)&loc_lds[tl][4 * j]);

        float acc = 0.f;
#pragma unroll 4
        for (int aa = 0; aa < 32; ++aa) {
            const int a = aq + 4 * aa;   // interleaved: 4 lanes -> 4 distinct banks
            float e = pq_lds[a] + pm_lds[tl][a];
#pragma unroll
            for (int j = 0; j < 8; ++j) {
                float4 w4 = *((const float4*)&wl_lds[a][4 * j]);
                e += w4.x * lr[4*j] + w4.y * lr[4*j+1] + w4.z * lr[4*j+2] + w4.w * lr[4*j+3];
            }
            // fast tanh: 1 - 2/(1+exp(2e)); ~5 VALU ops, abs err ~1e-6
            float ex = __expf(2.f * e);
            float th = 1.f - 2.f * __builtin_amdgcn_rcpf(1.f + ex);
            acc += v_lds[a] * th;
        }
        // reduce the 4 adjacent lanes sharing t
        acc += __shfl_xor(acc, 1, 64);
        acc += __shfl_xor(acc, 2, 64);
        if (aq == 0 && (t0 + tl) < T)
            energy[b * T + t0 + tl] = acc;
    }
}

// ---------------------------------------------------------------------------
// Kernel 3: softmax over T per batch row; writes weights to d_out tail and
// zeroes the context region of d_out (harness poisons d_out with 0xAA).
// ---------------------------------------------------------------------------
__global__ __launch_bounds__(256) void softmax_kernel(
    const float* __restrict__ energy,        // (B, T) in ws
    const unsigned char* __restrict__ mask,  // (B, T) bool
    float* __restrict__ out)                 // [B*512 ctx][B*1000 weights]
{
    int b   = blockIdx.x;
    int tid = threadIdx.x;

    // zero context region for kernel 4's atomics
    for (int i = tid; i < EMB_DIM; i += 256) out[b * EMB_DIM + i] = 0.f;

    __shared__ float red[4];
    float e[4];
    float mx = -INFINITY;
#pragma unroll
    for (int j = 0; j < 4; ++j) {
        int t = tid + j * 256;
        if (t < T) {
            float val = energy[b * T + t];
            if (mask[b * T + t]) val = -INFINITY;
            e[j] = val;
            mx = fmaxf(mx, val);
        } else e[j] = -INFINITY;
    }
#pragma unroll
    for (int off = 32; off > 0; off >>= 1)
        mx = fmaxf(mx, __shfl_down(mx, off, 64));
    if ((tid & 63) == 0) red[tid >> 6] = mx;
    __syncthreads();
    mx = fmaxf(fmaxf(red[0], red[1]), fmaxf(red[2], red[3]));
    __syncthreads();

    float sum = 0.f;
    float ex[4];
#pragma unroll
    for (int j = 0; j < 4; ++j) {
        ex[j] = (e[j] == -INFINITY) ? 0.f : expf(e[j] - mx);
        sum += ex[j];
    }
#pragma unroll
    for (int off = 32; off > 0; off >>= 1)
        sum += __shfl_down(sum, off, 64);
    if ((tid & 63) == 0) red[tid >> 6] = sum;
    __syncthreads();
    sum = red[0] + red[1] + red[2] + red[3];
    float inv = 1.f / sum;
#pragma unroll
    for (int j = 0; j < 4; ++j) {
        int t = tid + j * 256;
        if (t < T) out[B * EMB_DIM + b * T + t] = ex[j] * inv;
    }
}

// ---------------------------------------------------------------------------
// Kernel 4: context[b][e] = sum_t w[b][t] * memory[b][t][e]
// R4 (-14us, predicted -60) showed implicit unrolling does NOT batch loads.
// This version forces ILP structurally: phase A issues 20 independent
// global_load_dwordx4 into register arrays (no consumer in between), phase B
// accumulates. Data deps force >=20 loads in flight per thread. CHUNK 40
// (grid 64x25=1600 blocks, 6400 waves) for scheduler slack + ramp coverage.
// ---------------------------------------------------------------------------
__global__ __launch_bounds__(256) void context_kernel(
    const float* __restrict__ memory,   // (B, T, 512)
    const float* __restrict__ w,        // weights at d_out + B*512
    float* __restrict__ ctx)            // d_out context region
{
    __shared__ float w_lds[CHUNK];
    __shared__ float red[4][EMB_DIM];   // 8 KB partials

    const int b   = blockIdx.x;
    const int t0  = blockIdx.y * CHUNK;
    const int tid = threadIdx.x;
    const int e8  = tid & 63;   // pair-of-float4 index within 512-float row
    const int ts  = tid >> 6;   // wave id 0..3: t interleave

    if (tid < CHUNK) w_lds[tid] = w[b * T + t0 + tid];

    const float4* base = (const float4*)(memory + (size_t)b * T * EMB_DIM)
                         + (size_t)t0 * 128 + e8 * 2;

    // Phase A: issue all 20 loads before any consumer.
    float4 m0[10], m1[10];
#pragma unroll
    for (int i = 0; i < 10; ++i) {
        const float4* row = base + (size_t)(ts + 4 * i) * 128;
        m0[i] = row[0];
        m1[i] = row[1];
    }
    __syncthreads();   // w_lds ready (placed after load issue: lgkm vs vm independent)

    // Phase B: accumulate.
    float4 acc0 = {0.f, 0.f, 0.f, 0.f};
    float4 acc1 = {0.f, 0.f, 0.f, 0.f};
#pragma unroll
    for (int i = 0; i < 10; ++i) {
        float wt = w_lds[ts + 4 * i];   // wave-uniform LDS broadcast
        acc0.x += wt * m0[i].x; acc0.y += wt * m0[i].y;
        acc0.z += wt * m0[i].z; acc0.w += wt * m0[i].w;
        acc1.x += wt * m1[i].x; acc1.y += wt * m1[i].y;
        acc1.z += wt * m1[i].z; acc1.w += wt * m1[i].w;
    }

    // block reduction: 4 t-interleave waves hit the same 8 output floats
    float* r = &red[ts][e8 * 8];
    r[0] = acc0.x; r[1] = acc0.y; r[2] = acc0.z; r[3] = acc0.w;
    r[4] = acc1.x; r[5] = acc1.y; r[6] = acc1.z; r[7] = acc1.w;
    __syncthreads();
    for (int i = tid; i < EMB_DIM; i += 256) {
        float s = red[0][i] + red[1][i] + red[2][i] + red[3][i];
        atomicAdd(ctx + b * EMB_DIM + i, s);
    }
}

// ---------------------------------------------------------------------------
extern "C" void kernel_launch(void* const* d_in, const int* in_sizes, int n_in,
                              void* d_out, int out_size, void* d_ws, size_t ws_size,
                              hipStream_t stream) {
    const float* hidden = (const float*)d_in[0];            // (64, 1024)
    const float* memory = (const float*)d_in[1];            // (64, 1000, 512)
    const float* pm     = (const float*)d_in[2];            // (64, 1000, 128)
    const float* aw     = (const float*)d_in[3];            // (64, 2, 1000)
    const unsigned char* mask = (const unsigned char*)d_in[4]; // (64, 1000) bool
    const float* Wq     = (const float*)d_in[5];            // (128, 1024)
    const float* cw     = (const float*)d_in[6];            // (32, 2, 31)
    const float* wl     = (const float*)d_in[7];            // (128, 32)
    const float* v      = (const float*)d_in[8];            // (1, 128)

    float* out = (float*)d_out;            // [B*512 context][B*1000 weights]

    // workspace layout
    float* pq_ws     = (float*)d_ws;                   // B*128
    float* energy_ws = pq_ws + B * ATT_DIM;            // B*T

    // 1) query projection: 8192 waves
    pq_kernel<<<dim3((B * ATT_DIM) / 4), dim3(256), 0, stream>>>(hidden, Wq, pq_ws);

    // 2) fused conv/proj/tanh/v-dot -> energy  (16 tiles of 64 t)
    energy_kernel<<<dim3(B, (T + ET - 1) / ET), dim3(256), 0, stream>>>(
        aw, cw, wl, pq_ws, pm, v, energy_ws);

    // 3) softmax (writes weights to out tail, zeroes context region)
    softmax_kernel<<<dim3(B), dim3(256), 0, stream>>>(energy_ws, mask, out);

    // 4) context accumulation (25 chunks of 40 t)
    context_kernel<<<dim3(B, T / CHUNK), dim3(256), 0, stream>>>(
        memory, out + B * EMB_DIM, out);
}